// Round 2
// baseline (375.515 us; speedup 1.0000x reference)
//
#include <hip/hip_runtime.h>
#include <hip/hip_bf16.h>

typedef __attribute__((ext_vector_type(4))) float  f32x4;
typedef __attribute__((ext_vector_type(8))) short  s16x8;
typedef __attribute__((ext_vector_type(4))) short  s16x4;

#define THR_  1.0e-4f   // LR * GAMMA
#define SC_   2.0e-3f   // 2 * LR

__device__ __forceinline__ unsigned short f2bf(float f) {
  union { __hip_bfloat16 b; unsigned short u; } cv;
  cv.b = __float2bfloat16(f);               // compiler emits v_cvt_pk_bf16_f32 pairs (RNE)
  return cv.u;
}

__device__ __forceinline__ float sthr(float v) {
  // v - clamp(v, -t, t)  -> v_med3_f32 + v_sub: exact soft-threshold
  return v - fmaxf(fminf(v, THR_), -THR_);
}

// ws layout (unsigned short elems):
//   [0     , 65536)  Gpk : B-frags of (-2LR * W@W^T), K=256,N=256 (kc 0..7, nt 0..15)
//   [65536 , 98304)  WTpk: B-frags of ( 2LR * W^T),   K=128,N=256 (kc 0..3, nt 0..15)
//   [98304 ,131072)  Wpk : B-frags of W,              K=256,N=128 (kc 0..7, nt 0..7)
// B-frag packing: elem j of lane l of frag (kc,nt) = M[kc*32 + (l>>4)*8 + j][nt*16 + (l&15)]
__global__ void sc_prep(const float* __restrict__ W, unsigned short* __restrict__ ws) {
  const int b = blockIdx.x;
  const int l = threadIdx.x;
  const int g = l >> 4, c = l & 15;
  if (b < 128) {                       // Gpk
    const int kc = b >> 4, nt = b & 15;
    const int n = nt * 16 + c;
    const int k0 = kc * 32 + g * 8;
    float s[8];
    #pragma unroll
    for (int j = 0; j < 8; ++j) s[j] = 0.0f;
    for (int i = 0; i < 128; ++i) {
      const float wn = W[n * 128 + i];
      #pragma unroll
      for (int j = 0; j < 8; ++j) s[j] += W[(k0 + j) * 128 + i] * wn;
    }
    unsigned short* dst = ws + ((unsigned)b * 64u + l) * 8u;
    #pragma unroll
    for (int j = 0; j < 8; ++j) dst[j] = f2bf(-SC_ * s[j]);
  } else if (b < 192) {                // WTpk
    const int bb = b - 128;
    const int kc = bb >> 4, nt = bb & 15;
    const int n = nt * 16 + c;
    const int k0 = kc * 32 + g * 8;
    unsigned short* dst = ws + 65536u + ((unsigned)bb * 64u + l) * 8u;
    #pragma unroll
    for (int j = 0; j < 8; ++j) dst[j] = f2bf(SC_ * W[n * 128 + (k0 + j)]);
  } else {                             // Wpk
    const int bb = b - 192;
    const int kc = bb >> 3, nt = bb & 7;
    const int n = nt * 16 + c;
    const int k0 = kc * 32 + g * 8;
    unsigned short* dst = ws + 98304u + ((unsigned)bb * 64u + l) * 8u;
    #pragma unroll
    for (int j = 0; j < 8; ++j) dst[j] = f2bf(W[(k0 + j) * 128 + n]);
  }
}

// x-tile LDS layout: XB[kc][row][inner64B], row stride 80B (pad -> odd*16 permutes
// bank-quads, 2-way max on ds_read_b128 = free), kc stride 5120B, buffer = 40960B.
// All DS addresses = one base VGPR + compile-time immediate.
__global__ __launch_bounds__(512, 4) void sc_fused(
    const float* __restrict__ inp,
    const unsigned short* __restrict__ wsp,
    float* __restrict__ outp)
{
  __shared__ __align__(16) unsigned char lds[81920];  // XB0 [0,40960), XB1/INB [40960,81920)

  const int tid = threadIdx.x;
  const int l = tid & 63;
  const int w = tid >> 6;
  const int g = l >> 4;
  const int c = l & 15;
  const long row0 = (long)blockIdx.x * 64;

  // A-read base: row = rt*16 + c -> rb + kc*5120 + rt*1280
  const int rb0 = c * 80 + g * 16;
  const int rb1 = rb0 + 40960;
  // x-write base: row = rt*16 + g*4 + r, col = w*32 + n*16 + c -> wb + rt*1280 + r*80 + n*32
  const int wb0 = w * 5120 + g * 320 + c * 2;
  const int wb1 = wb0 + 40960;

  // ---- stage inputs -> INB (buf1 region): in[row][i] at [i>>5][row][(i&31)*2] ----
  #pragma unroll
  for (int rep = 0; rep < 4; ++rep) {
    const int flat = rep * 512 + tid;
    const int r = flat >> 5;
    const int c4 = flat & 31;
    const f32x4 v = *reinterpret_cast<const f32x4*>(inp + (row0 + r) * 128 + c4 * 4);
    s16x4 p;
    p[0] = (short)f2bf(v[0]); p[1] = (short)f2bf(v[1]);
    p[2] = (short)f2bf(v[2]); p[3] = (short)f2bf(v[3]);
    *reinterpret_cast<s16x4*>(lds + 40960 + (c4 >> 3) * 5120 + r * 80 + (c4 & 7) * 8) = p;
  }

  // ---- B-frags for c-phase (2LR * W^T) ----
  s16x8 bfrag[16];
  #pragma unroll
  for (int kc = 0; kc < 4; ++kc)
    #pragma unroll
    for (int n = 0; n < 2; ++n)
      bfrag[kc * 2 + n] = *reinterpret_cast<const s16x8*>(
          wsp + 65536u + ((unsigned)(kc * 16 + (w * 2 + n)) * 64u + l) * 8u);

  __syncthreads();

  // ---- c = 2LR * in @ W^T ----
  f32x4 creg[4][2], xreg[4][2], acc[4][2];
  #pragma unroll
  for (int rt = 0; rt < 4; ++rt)
    #pragma unroll
    for (int n = 0; n < 2; ++n)
      acc[rt][n] = (f32x4){0.f, 0.f, 0.f, 0.f};

  #pragma unroll
  for (int kc = 0; kc < 4; ++kc) {
    s16x8 a[4];
    #pragma unroll
    for (int rt = 0; rt < 4; ++rt)
      a[rt] = *reinterpret_cast<const s16x8*>(lds + rb1 + kc * 5120 + rt * 1280);
    __builtin_amdgcn_s_setprio(1);
    #pragma unroll
    for (int rt = 0; rt < 4; ++rt)
      #pragma unroll
      for (int n = 0; n < 2; ++n)
        acc[rt][n] = __builtin_amdgcn_mfma_f32_16x16x32_bf16(
            a[rt], bfrag[kc * 2 + n], acc[rt][n], 0, 0, 0);
    __builtin_amdgcn_s_setprio(0);
  }

  // x1 = sthr(c); write x1 -> buf0
  #pragma unroll
  for (int rt = 0; rt < 4; ++rt)
    #pragma unroll
    for (int n = 0; n < 2; ++n) {
      creg[rt][n] = acc[rt][n];
      #pragma unroll
      for (int r = 0; r < 4; ++r) {
        const float xv = sthr(acc[rt][n][r]);
        xreg[rt][n][r] = xv;
        *reinterpret_cast<unsigned short*>(lds + wb0 + rt * 1280 + r * 80 + n * 32) = f2bf(xv);
      }
    }

  // ---- B-frags for steps (-2LR * G) ----
  #pragma unroll
  for (int kc = 0; kc < 8; ++kc)
    #pragma unroll
    for (int n = 0; n < 2; ++n)
      bfrag[kc * 2 + n] = *reinterpret_cast<const s16x8*>(
          wsp + ((unsigned)(kc * 16 + (w * 2 + n)) * 64u + l) * 8u);

  // ---- one ISTA step: x <- sthr(x + c - 2LR*(x@G)) ----
  auto STEP = [&](const int rb, const int wb) {
    __syncthreads();
    #pragma unroll
    for (int rt = 0; rt < 4; ++rt)
      #pragma unroll
      for (int n = 0; n < 2; ++n)
        acc[rt][n] = creg[rt][n] + xreg[rt][n];
    #pragma unroll
    for (int kc = 0; kc < 8; ++kc) {
      s16x8 a[4];
      #pragma unroll
      for (int rt = 0; rt < 4; ++rt)
        a[rt] = *reinterpret_cast<const s16x8*>(lds + rb + kc * 5120 + rt * 1280);
      __builtin_amdgcn_s_setprio(1);
      #pragma unroll
      for (int rt = 0; rt < 4; ++rt)
        #pragma unroll
        for (int n = 0; n < 2; ++n)
          acc[rt][n] = __builtin_amdgcn_mfma_f32_16x16x32_bf16(
              a[rt], bfrag[kc * 2 + n], acc[rt][n], 0, 0, 0);
      __builtin_amdgcn_s_setprio(0);
    }
    #pragma unroll
    for (int rt = 0; rt < 4; ++rt)
      #pragma unroll
      for (int n = 0; n < 2; ++n)
        #pragma unroll
        for (int r = 0; r < 4; ++r) {
          const float xv = sthr(acc[rt][n][r]);
          xreg[rt][n][r] = xv;
          *reinterpret_cast<unsigned short*>(lds + wb + rt * 1280 + r * 80 + n * 32) = f2bf(xv);
        }
  };

  // 9 steps: (rb0,wb1),(rb1,wb0) x4 pairs + final (rb0,wb1) -> x10 lands in buf1
  #pragma unroll 1
  for (int p = 0; p < 4; ++p) {
    STEP(rb0, wb1);
    STEP(rb1, wb0);
  }
  STEP(rb0, wb1);

  // ---- out = x @ W ; wave w owns out cols [w*16, w*16+16) ----
  __syncthreads();
  s16x8 wfr[8];
  #pragma unroll
  for (int kc = 0; kc < 8; ++kc)
    wfr[kc] = *reinterpret_cast<const s16x8*>(
        wsp + 98304u + ((unsigned)(kc * 8 + w) * 64u + l) * 8u);
  f32x4 oacc[4];
  #pragma unroll
  for (int rt = 0; rt < 4; ++rt) oacc[rt] = (f32x4){0.f, 0.f, 0.f, 0.f};
  #pragma unroll
  for (int kc = 0; kc < 8; ++kc) {
    s16x8 a[4];
    #pragma unroll
    for (int rt = 0; rt < 4; ++rt)
      a[rt] = *reinterpret_cast<const s16x8*>(lds + rb1 + kc * 5120 + rt * 1280);
    __builtin_amdgcn_s_setprio(1);
    #pragma unroll
    for (int rt = 0; rt < 4; ++rt)
      oacc[rt] = __builtin_amdgcn_mfma_f32_16x16x32_bf16(a[rt], wfr[kc], oacc[rt], 0, 0, 0);
    __builtin_amdgcn_s_setprio(0);
  }
  #pragma unroll
  for (int rt = 0; rt < 4; ++rt)
    #pragma unroll
    for (int r = 0; r < 4; ++r)
      outp[(row0 + rt * 16 + g * 4 + r) * 128 + w * 16 + c] = oacc[rt][r];
}

extern "C" void kernel_launch(void* const* d_in, const int* in_sizes, int n_in,
                              void* d_out, int out_size, void* d_ws, size_t ws_size,
                              hipStream_t stream) {
  const float* inp = (const float*)d_in[0];
  const float* W   = (const float*)d_in[1];
  unsigned short* ws = (unsigned short*)d_ws;   // needs 256 KiB
  float* outp = (float*)d_out;
  const int B = in_sizes[0] / 128;              // 131072
  sc_prep<<<256, 64, 0, stream>>>(W, ws);
  sc_fused<<<B / 64, 512, 0, stream>>>(inp, ws, outp);
}

// Round 3
// 172.664 us; speedup vs baseline: 2.1748x; 2.1748x over previous
//
#include <hip/hip_runtime.h>
#include <hip/hip_bf16.h>

typedef __attribute__((ext_vector_type(4))) float  f32x4;
typedef __attribute__((ext_vector_type(8))) short  s16x8;
typedef __attribute__((ext_vector_type(4))) short  s16x4;

#define THR_  1.0e-4f   // LR * GAMMA
#define SC_   2.0e-3f   // 2 * LR

__device__ __forceinline__ unsigned short f2bf(float f) {
  union { __hip_bfloat16 b; unsigned short u; } cv;
  cv.b = __float2bfloat16(f);               // RNE, compiler may pair into v_cvt_pk_bf16_f32
  return cv.u;
}

__device__ __forceinline__ float sthr(float v) {
  // v - clamp(v, -t, t)  -> v_med3_f32 + v_sub: exact soft-threshold
  return v - fmaxf(fminf(v, THR_), -THR_);
}

// ws layout (unsigned short elems):
//   [0     , 65536)  Gpk : B-frags of (-2LR * W@W^T), K=256,N=256 (kc 0..7, nt 0..15)
//   [65536 , 98304)  WTpk: B-frags of ( 2LR * W^T),   K=128,N=256 (kc 0..3, nt 0..15)
//   [98304 ,131072)  Wpk : B-frags of W,              K=256,N=128 (kc 0..7, nt 0..7)
// B-frag packing: elem j of lane l of frag (kc,nt) = M[kc*32 + (l>>4)*8 + j][nt*16 + (l&15)]
__global__ void sc_prep(const float* __restrict__ W, unsigned short* __restrict__ ws) {
  const int b = blockIdx.x;
  const int l = threadIdx.x;
  const int g = l >> 4, c = l & 15;
  if (b < 128) {                       // Gpk
    const int kc = b >> 4, nt = b & 15;
    const int n = nt * 16 + c;
    const int k0 = kc * 32 + g * 8;
    float s[8];
    #pragma unroll
    for (int j = 0; j < 8; ++j) s[j] = 0.0f;
    for (int i = 0; i < 128; ++i) {
      const float wn = W[n * 128 + i];
      #pragma unroll
      for (int j = 0; j < 8; ++j) s[j] += W[(k0 + j) * 128 + i] * wn;
    }
    unsigned short* dst = ws + ((unsigned)b * 64u + l) * 8u;
    #pragma unroll
    for (int j = 0; j < 8; ++j) dst[j] = f2bf(-SC_ * s[j]);
  } else if (b < 192) {                // WTpk
    const int bb = b - 128;
    const int kc = bb >> 4, nt = bb & 15;
    const int n = nt * 16 + c;
    const int k0 = kc * 32 + g * 8;
    unsigned short* dst = ws + 65536u + ((unsigned)bb * 64u + l) * 8u;
    #pragma unroll
    for (int j = 0; j < 8; ++j) dst[j] = f2bf(SC_ * W[n * 128 + (k0 + j)]);
  } else {                             // Wpk
    const int bb = b - 192;
    const int kc = bb >> 3, nt = bb & 7;
    const int n = nt * 16 + c;
    const int k0 = kc * 32 + g * 8;
    unsigned short* dst = ws + 98304u + ((unsigned)bb * 64u + l) * 8u;
    #pragma unroll
    for (int j = 0; j < 8; ++j) dst[j] = f2bf(W[(k0 + j) * 128 + n]);
  }
}

// 4 waves/block, 32 batch rows/block, each wave covers all rows x 64 cols
// (N_wave=64 halves the x-broadcast LDS traffic vs N_wave=32).
// x-tile LDS layout: [kc][row][64B], row stride 80 B (odd*16 pad -> 2-way max
// on ds_read_b128 = free), kc stride 2560 B, buffer = 20480 B. All DS
// addresses = one base VGPR + compile-time immediate.
__global__ __launch_bounds__(256, 2) void sc_fused(
    const float* __restrict__ inp,
    const unsigned short* __restrict__ wsp,
    float* __restrict__ outp)
{
  __shared__ __align__(16) unsigned char lds[40960];  // XB0 [0,20480), XB1/INB [20480,40960)

  const int tid = threadIdx.x;
  const int l = tid & 63;
  const int w = tid >> 6;          // 0..3
  const int g = l >> 4;
  const int c = l & 15;
  const long row0 = (long)blockIdx.x * 32;

  // A-read base: row = rt2*16 + c -> srb + kc*2560 + rt2*1280
  const int srb0 = c * 80 + g * 16;
  const int srb1 = srb0 + 20480;
  // x-write base: row = rt2*16 + g*4 + r, col = w*64 + n*16 + c
  //   -> wb + (n>>1)*2560 + rt2*1280 + r*80 + (n&1)*32
  const int wb0 = w * 5120 + g * 320 + c * 2;
  const int wb1 = wb0 + 20480;

  // ---- stage inputs -> INB (buf1 region): in[row][i] at [i>>5][row][(i&31)*2] ----
  #pragma unroll
  for (int rep = 0; rep < 4; ++rep) {
    const int flat = rep * 256 + tid;           // 0..1023 float4s (32 rows x 32)
    const int r = flat >> 5;
    const int c4 = flat & 31;
    const f32x4 v = *reinterpret_cast<const f32x4*>(inp + (row0 + r) * 128 + c4 * 4);
    s16x4 p;
    p[0] = (short)f2bf(v[0]); p[1] = (short)f2bf(v[1]);
    p[2] = (short)f2bf(v[2]); p[3] = (short)f2bf(v[3]);
    *reinterpret_cast<s16x4*>(lds + 20480 + (c4 >> 3) * 2560 + r * 80 + (c4 & 7) * 8) = p;
  }

  // ---- B-frags for c-phase (2LR * W^T), nt = w*4+n ----
  s16x8 bfrag[32];
  #pragma unroll
  for (int kc = 0; kc < 4; ++kc)
    #pragma unroll
    for (int n = 0; n < 4; ++n)
      bfrag[kc * 4 + n] = *reinterpret_cast<const s16x8*>(
          wsp + 65536u + ((unsigned)(kc * 16 + (w * 4 + n)) * 64u + l) * 8u);

  __syncthreads();

  // ---- c = 2LR * in @ W^T ; xacc doubles as accumulator and x ----
  f32x4 xacc[2][4], creg[2][4];
  #pragma unroll
  for (int rt = 0; rt < 2; ++rt)
    #pragma unroll
    for (int n = 0; n < 4; ++n)
      xacc[rt][n] = (f32x4){0.f, 0.f, 0.f, 0.f};

  #pragma unroll
  for (int kc = 0; kc < 4; ++kc) {
    s16x8 a[2];
    #pragma unroll
    for (int rt = 0; rt < 2; ++rt)
      a[rt] = *reinterpret_cast<const s16x8*>(lds + srb1 + kc * 2560 + rt * 1280);
    __builtin_amdgcn_s_setprio(1);
    #pragma unroll
    for (int rt = 0; rt < 2; ++rt)
      #pragma unroll
      for (int n = 0; n < 4; ++n)
        xacc[rt][n] = __builtin_amdgcn_mfma_f32_16x16x32_bf16(
            a[rt], bfrag[kc * 4 + n], xacc[rt][n], 0, 0, 0);
    __builtin_amdgcn_s_setprio(0);
  }

  // x1 = sthr(c); write x1 -> buf0
  #pragma unroll
  for (int rt = 0; rt < 2; ++rt)
    #pragma unroll
    for (int n = 0; n < 4; ++n) {
      creg[rt][n] = xacc[rt][n];
      #pragma unroll
      for (int r = 0; r < 4; ++r) {
        const float xv = sthr(xacc[rt][n][r]);
        xacc[rt][n][r] = xv;
        *reinterpret_cast<unsigned short*>(
            lds + wb0 + (n >> 1) * 2560 + rt * 1280 + r * 80 + (n & 1) * 32) = f2bf(xv);
      }
    }

  // ---- B-frags for steps (-2LR * G), nt = w*4+n ----
  #pragma unroll
  for (int kc = 0; kc < 8; ++kc)
    #pragma unroll
    for (int n = 0; n < 4; ++n)
      bfrag[kc * 4 + n] = *reinterpret_cast<const s16x8*>(
          wsp + ((unsigned)(kc * 16 + (w * 4 + n)) * 64u + l) * 8u);

  // ---- one ISTA step: x <- sthr(x + c - 2LR*(x@G)) ----
  auto STEP = [&](const int rb, const int wb) {
    __syncthreads();
    #pragma unroll
    for (int rt = 0; rt < 2; ++rt)
      #pragma unroll
      for (int n = 0; n < 4; ++n)
        xacc[rt][n] += creg[rt][n];
    #pragma unroll
    for (int kc = 0; kc < 8; ++kc) {
      s16x8 a[2];
      #pragma unroll
      for (int rt = 0; rt < 2; ++rt)
        a[rt] = *reinterpret_cast<const s16x8*>(lds + rb + kc * 2560 + rt * 1280);
      __builtin_amdgcn_s_setprio(1);
      #pragma unroll
      for (int rt = 0; rt < 2; ++rt)
        #pragma unroll
        for (int n = 0; n < 4; ++n)
          xacc[rt][n] = __builtin_amdgcn_mfma_f32_16x16x32_bf16(
              a[rt], bfrag[kc * 4 + n], xacc[rt][n], 0, 0, 0);
      __builtin_amdgcn_s_setprio(0);
    }
    #pragma unroll
    for (int rt = 0; rt < 2; ++rt)
      #pragma unroll
      for (int n = 0; n < 4; ++n)
        #pragma unroll
        for (int r = 0; r < 4; ++r) {
          const float xv = sthr(xacc[rt][n][r]);
          xacc[rt][n][r] = xv;
          *reinterpret_cast<unsigned short*>(
              lds + wb + (n >> 1) * 2560 + rt * 1280 + r * 80 + (n & 1) * 32) = f2bf(xv);
        }
  };

  // 9 steps: x1 in buf0; alternate; x10 lands in buf1
  #pragma unroll 1
  for (int p = 0; p < 4; ++p) {
    STEP(srb0, wb1);
    STEP(srb1, wb0);
  }
  STEP(srb0, wb1);

  // ---- out = x @ W ; wave w owns out cols [w*32, w*32+32) ----
  __syncthreads();
  s16x8 wfr[16];
  #pragma unroll
  for (int kc = 0; kc < 8; ++kc)
    #pragma unroll
    for (int n2 = 0; n2 < 2; ++n2)
      wfr[kc * 2 + n2] = *reinterpret_cast<const s16x8*>(
          wsp + 98304u + ((unsigned)(kc * 8 + (w * 2 + n2)) * 64u + l) * 8u);
  f32x4 oacc[2][2];
  #pragma unroll
  for (int rt = 0; rt < 2; ++rt)
    #pragma unroll
    for (int n2 = 0; n2 < 2; ++n2)
      oacc[rt][n2] = (f32x4){0.f, 0.f, 0.f, 0.f};
  #pragma unroll
  for (int kc = 0; kc < 8; ++kc) {
    s16x8 a[2];
    #pragma unroll
    for (int rt = 0; rt < 2; ++rt)
      a[rt] = *reinterpret_cast<const s16x8*>(lds + srb1 + kc * 2560 + rt * 1280);
    __builtin_amdgcn_s_setprio(1);
    #pragma unroll
    for (int rt = 0; rt < 2; ++rt)
      #pragma unroll
      for (int n2 = 0; n2 < 2; ++n2)
        oacc[rt][n2] = __builtin_amdgcn_mfma_f32_16x16x32_bf16(
            a[rt], wfr[kc * 2 + n2], oacc[rt][n2], 0, 0, 0);
    __builtin_amdgcn_s_setprio(0);
  }
  #pragma unroll
  for (int rt = 0; rt < 2; ++rt)
    #pragma unroll
    for (int n2 = 0; n2 < 2; ++n2)
      #pragma unroll
      for (int r = 0; r < 4; ++r)
        outp[(row0 + rt * 16 + g * 4 + r) * 128 + w * 32 + n2 * 16 + c] = oacc[rt][n2][r];
}

extern "C" void kernel_launch(void* const* d_in, const int* in_sizes, int n_in,
                              void* d_out, int out_size, void* d_ws, size_t ws_size,
                              hipStream_t stream) {
  const float* inp = (const float*)d_in[0];
  const float* W   = (const float*)d_in[1];
  unsigned short* ws = (unsigned short*)d_ws;   // needs 256 KiB
  float* outp = (float*)d_out;
  const int B = in_sizes[0] / 128;              // 131072
  sc_prep<<<256, 64, 0, stream>>>(W, ws);
  sc_fused<<<B / 32, 256, 0, stream>>>(inp, ws, outp);
}